// Round 10
// baseline (362.570 us; speedup 1.0000x reference)
//
#include <hip/hip_runtime.h>
#include <hip/hip_bf16.h>
#include <math.h>

// ---------------------------------------------------------------------------
// RealSymplecticReactionDiffusion2D — round 8 kernel (resubmit, infra failure)
//  B=8, N=4096 (64x64), d=768, k_steps=4 (read from device)
// Stages:
//  1) transpose_x (FUSED column-sum partials for mean-pool) -> xT + partial
//  2) pool_reduce  -> pooled[8][768]
//  3) gamma_kernel -> gamma[8][768]
//  4) cvt_bf16 (W_out -> bf16)
//  5) pde_kernel: ONE WAVE per (b,c) channel — 8x8 lane grid, 8x8 register
//     patch per lane; halo via 32 shfls; no LDS/barriers (R7, ~55us).
//  6) transpose_uv -> A [32768][1536] bf16
//  7) gemm_kernel: bf16 MFMA, 128x128 tile, BK=32 (LDS 64KB->32KB ->
//     4 blocks/CU, fixes occupancy-starved barrier stalls), re-derived XOR
//     swizzle for 64B rows, dbuf + counted vmcnt(4), XCD-chunked remap.
//  Aliases: xT ~ A  (xT dead before A written); partial ~ uv (dead before pde)
// ---------------------------------------------------------------------------

typedef __attribute__((ext_vector_type(8))) short short8v;
typedef __attribute__((ext_vector_type(4))) float float4v;

static __device__ __forceinline__ unsigned short f2bf(float f) {
  unsigned u = __builtin_bit_cast(unsigned, f);
  u += 0x7FFFu + ((u >> 16) & 1u);   // round-to-nearest-even
  return (unsigned short)(u >> 16);
}

static __device__ __forceinline__ float softplusf(float x) {
  return (x > 20.0f) ? x : log1pf(expf(x));
}

// ---------------- transpose x [B,N,768] -> xT [B,768,N]  (+ pool partials) --
__global__ __launch_bounds__(256) void transpose_x_kernel(const float* __restrict__ x,
                                                          float* __restrict__ xT,
                                                          float* __restrict__ partial) {
  __shared__ float tile[64][65];
  __shared__ float red[4][64];
  const int c0 = blockIdx.x * 64;   // 12 tiles
  const int n0 = blockIdx.y * 64;   // 64 tiles
  const int b  = blockIdx.z;        // 8
  const int tl = threadIdx.x & 63;
  const int tw = threadIdx.x >> 6;  // 0..3
  const float* src = x + ((size_t)b * 4096 + n0) * 768 + c0;
  float s = 0.0f;
  #pragma unroll
  for (int j = 0; j < 16; ++j) {
    const int n = j * 4 + tw;
    const float val = src[(size_t)n * 768 + tl];
    tile[n][tl] = val;
    s += val;
  }
  red[tw][tl] = s;
  __syncthreads();
  // partial[n-chunk][b][c] ; n-chunk = blockIdx.y (64 chunks)
  if (tw == 0) {
    partial[((size_t)blockIdx.y * 8 + b) * 768 + c0 + tl] =
        red[0][tl] + red[1][tl] + red[2][tl] + red[3][tl];
  }
  float* dst = xT + ((size_t)b * 768 + c0) * 4096 + n0;
  #pragma unroll
  for (int j = 0; j < 16; ++j) {
    const int cc = j * 4 + tw;
    dst[(size_t)cc * 4096 + tl] = tile[tl][cc];
  }
}

__global__ void pool_reduce_kernel(const float* __restrict__ partial, float* __restrict__ pooled) {
  const int idx = blockIdx.x * 256 + threadIdx.x;   // 0..6143 = b*768+c
  float s = 0.0f;
  #pragma unroll
  for (int j = 0; j < 64; ++j) s += partial[(size_t)j * 6144 + idx];
  pooled[idx] = s * (1.0f / 4096.0f);
}

// ---------------- diffusion gate ----------------
__global__ void gamma_kernel(const float* __restrict__ pooled, const float* __restrict__ Wg,
                             const float* __restrict__ bg, float* __restrict__ gamma) {
  // grid 1536 x 256 threads; each wave computes one output o = b*768 + j
  const int lane = threadIdx.x & 63;
  const int w = threadIdx.x >> 6;
  const int o = blockIdx.x * 4 + w;
  const int b = o / 768;
  const int j = o - b * 768;
  const float* pr = pooled + b * 768;
  const float* wr = Wg + (size_t)j * 768;
  float s = 0.0f;
  #pragma unroll
  for (int c = lane; c < 768; c += 64) s += pr[c] * wr[c];
  #pragma unroll
  for (int off = 32; off > 0; off >>= 1) s += __shfl_down(s, off);
  if (lane == 0) {
    float gin = s + bg[j];
    gamma[o] = fminf(softplusf(gin), 0.05f);
  }
}

// ---------------- W_out -> bf16 ----------------
__global__ void cvt_bf16_kernel(const float* __restrict__ src, unsigned short* __restrict__ dst, int n) {
  int i = blockIdx.x * 256 + threadIdx.x;
  if (i < n) dst[i] = f2bf(src[i]);
}

// ---------------- symplectic reaction-diffusion PDE (wave-per-channel) ------
__global__ __launch_bounds__(256, 2) void pde_kernel(
    const float* __restrict__ xT, const float* __restrict__ gamma,
    const float* __restrict__ alpha, const float* __restrict__ beta,
    const int* __restrict__ kp, unsigned short* __restrict__ uv) {
  const int w = threadIdx.x >> 6;          // wave 0..3 (independent channels)
  const int lane = threadIdx.x & 63;
  const int cidx = blockIdx.x * 4 + w;     // 0..6143
  const int b = cidx / 768;
  const int c = cidx - b * 768;
  const int lx = lane & 7;
  const int ly = lane >> 3;

  int ks = *kp; if (ks < 1) ks = 1;
  const float dt = 1.0f / (float)ks;
  const float hdt = 0.5f * dt;
  const float ae = 0.2f * tanhf(alpha[c]);
  const float be = fmaxf(softplusf(beta[c]), 1e-4f);
  const float g = gamma[b * 768 + c];
  const float c1n = -0.5f * dt * g;   // v -= c1*lap  ->  v += c1n*lap
  const float c2p = dt * g;

  const int laneL = (ly << 3) | ((lx + 7) & 7);
  const int laneR = (ly << 3) | ((lx + 1) & 7);
  const int laneU = (((ly + 7) & 7) << 3) | lx;   // holds rows above (row-1)
  const int laneD = (((ly + 1) & 7) << 3) | lx;   // holds rows below (row+1)

  float u[64], v[64];
  const float* xp = xT + ((size_t)b * 768 + c) * 4096;
  #pragma unroll
  for (int r = 0; r < 8; ++r) {
    const float4* src = (const float4*)(xp + (ly * 8 + r) * 64 + lx * 8);
    const float4 a0 = src[0], a1 = src[1];
    u[r * 8 + 0] = a0.x; u[r * 8 + 1] = a0.y; u[r * 8 + 2] = a0.z; u[r * 8 + 3] = a0.w;
    u[r * 8 + 4] = a1.x; u[r * 8 + 5] = a1.y; u[r * 8 + 6] = a1.z; u[r * 8 + 7] = a1.w;
  }
  #pragma unroll
  for (int i = 0; i < 64; ++i) v[i] = 0.0f;

  // G += COEF * lap(F): halo via 32 shfls, interior in-register.
  #define LAP_PHASE(F, G, COEF)                                               \
    {                                                                         \
      float lh[8], rh[8], uh[8], dh[8];                                       \
      _Pragma("unroll")                                                       \
      for (int r = 0; r < 8; ++r) {                                           \
        lh[r] = __shfl(F[r * 8 + 7], laneL);   /* left lane's right col  */   \
        rh[r] = __shfl(F[r * 8 + 0], laneR);   /* right lane's left col  */   \
        uh[r] = __shfl(F[56 + r], laneU);      /* up lane's bottom row, col r */ \
        dh[r] = __shfl(F[r], laneD);           /* down lane's top row, col r  */ \
      }                                                                       \
      _Pragma("unroll")                                                       \
      for (int r = 0; r < 8; ++r) {                                           \
        _Pragma("unroll")                                                     \
        for (int j = 0; j < 8; ++j) {                                         \
          const float lf = (j == 0) ? lh[r] : F[r * 8 + j - 1];               \
          const float rt = (j == 7) ? rh[r] : F[r * 8 + j + 1];               \
          const float up = (r == 0) ? uh[j] : F[(r - 1) * 8 + j];             \
          const float dn = (r == 7) ? dh[j] : F[(r + 1) * 8 + j];             \
          const float lap = (lf + rt) + (up + dn) - 4.0f * F[r * 8 + j];      \
          G[r * 8 + j] = fmaf((COEF), lap, G[r * 8 + j]);                     \
        }                                                                     \
      }                                                                       \
    }

  for (int s = 0; s < ks; ++s) {
    #pragma unroll
    for (int i = 0; i < 64; ++i) {
      const float q = u[i] * u[i] + v[i] * v[i];
      const float rate = fminf(fmaxf(ae - be * q, -1.0f), 1.0f);
      const float t = hdt * rate;
      u[i] = fmaf(t, u[i], u[i]);
      v[i] = fmaf(t, v[i], v[i]);
    }
    LAP_PHASE(u, v, c1n)
    LAP_PHASE(v, u, c2p)
    LAP_PHASE(u, v, c1n)
    #pragma unroll
    for (int i = 0; i < 64; ++i) {
      const float q = u[i] * u[i] + v[i] * v[i];
      const float rate = fminf(fmaxf(ae - be * q, -1.0f), 1.0f);
      const float t = hdt * rate;
      u[i] = fmaf(t, u[i], u[i]);
      v[i] = fmaf(t, v[i], v[i]);
    }
  }
  #undef LAP_PHASE

  // write out channel-major bf16: uv[b][c][n] = u, uv[b][768+c][n] = v
  unsigned short* up_ = uv + ((size_t)b * 1536 + c) * 4096;
  unsigned short* vp_ = up_ + (size_t)768 * 4096;
  #pragma unroll
  for (int r = 0; r < 8; ++r) {
    const int off = (ly * 8 + r) * 64 + lx * 8;
    short8v us, vs;
    #pragma unroll
    for (int j = 0; j < 8; ++j) {
      us[j] = (short)f2bf(u[r * 8 + j]);
      vs[j] = (short)f2bf(v[r * 8 + j]);
    }
    *(short8v*)(up_ + off) = us;
    *(short8v*)(vp_ + off) = vs;
  }
}

// ---------------- transpose uv [8][1536][4096] -> A [32768][1536] ----------------
__global__ void transpose_uv_kernel(const unsigned short* __restrict__ src,
                                    unsigned short* __restrict__ dst) {
  // grid (64, 24, 8), block 256
  __shared__ unsigned short tile[64][66];
  const int n0 = blockIdx.x * 64;
  const int k0 = blockIdx.y * 64;
  const int b = blockIdx.z;
  const int tx = threadIdx.x & 63;
  const int ty = threadIdx.x >> 6;   // 0..3
  const size_t sbase = ((size_t)b * 1536 + k0) * 4096 + n0;
  #pragma unroll
  for (int j = 0; j < 16; ++j) {
    const int k = ty + 4 * j;
    tile[k][tx] = src[sbase + (size_t)k * 4096 + tx];
  }
  __syncthreads();
  const size_t dbase = ((size_t)b * 4096 + n0) * 1536 + k0;
  #pragma unroll
  for (int j = 0; j < 16; ++j) {
    const int n = ty + 4 * j;
    dst[dbase + (size_t)n * 1536 + tx] = tile[tx][n];
  }
}

// ---------------- bf16 MFMA GEMM: out = A @ W^T + x*D ----------------
// BK=32, LDS 32KB (2 bufs x (A,B) x 128x32 bf16) -> 4 blocks/CU.
// Swizzle for 64B rows (4 x 16B slots): phys slot = logical ^ ((row>>1)&3).
//   staging src xor = (lane>>3)&3 ; read xor = (lane>>1)&3.
//   Bank check: 16 lanes/quarter -> 8 distinct 4-bank spans x 2 lanes = free.
// dbuf + counted vmcnt(4); XCD-chunked remap (R6).
__global__ __launch_bounds__(256, 4) void gemm_kernel(
    const unsigned short* __restrict__ A,   // [32768][1536] bf16
    const unsigned short* __restrict__ Bt,  // [768][1536]  bf16 (W_out, B^T layout)
    const float* __restrict__ x,            // [32768][768]
    const float* __restrict__ Dv,           // [768]
    float* __restrict__ out) {              // [32768][768]
  __shared__ __align__(16) unsigned short Als[2][128 * 32];
  __shared__ __align__(16) unsigned short Bls[2][128 * 32];
  const int tid = threadIdx.x;
  const int lane = tid & 63;
  const int w = tid >> 6;       // wave 0..3
  const int wr = w >> 1;        // wave row (2x2 waves, each 64x64 of C)
  const int wc = w & 1;

  // XCD-chunked remap: id -> (m-block, n-block). 1536 blocks, 8 XCDs.
  const int id = blockIdx.x;
  const int xcd = id & 7;
  const int seq = id >> 3;          // 0..191
  const int nb = seq % 6;
  const int mb = (seq / 6) * 8 + xcd;
  const int m0 = mb * 128;
  const int n0 = nb * 128;

  // staging: lane covers row (lane>>2), phys slot (lane&3);
  // fetch global logical slot (lane&3)^((lane>>3)&3)
  const int src_col = (((lane & 3) ^ ((lane >> 3) & 3)) * 8);   // halfwords
  // read side: logical slot q = lane>>4, row-phase xor = (lane>>1)&3
  const int soff = ((lane >> 4) ^ ((lane >> 1) & 3)) * 8;       // halfwords

  float4v acc[4][4];
  #pragma unroll
  for (int a = 0; a < 4; ++a)
    #pragma unroll
    for (int bq = 0; bq < 4; ++bq)
      acc[a][bq] = (float4v){0.f, 0.f, 0.f, 0.f};

  // per-thread: 4 global_load_lds (2 A + 2 B), 16B each; tile = 16KB total
  #define STAGE(bufi, kbase)                                                  \
    _Pragma("unroll")                                                         \
    for (int i = 0; i < 2; ++i) {                                             \
      const int rowblk = (i * 4 + w) * 16;                                    \
      const int row = rowblk + (lane >> 2);                                   \
      const int kk = (kbase) + src_col;                                       \
      __builtin_amdgcn_global_load_lds(                                       \
          (const __attribute__((address_space(1))) void*)(A + (size_t)(m0 + row) * 1536 + kk), \
          (__attribute__((address_space(3))) void*)(&Als[bufi][rowblk * 32]), 16, 0, 0); \
      __builtin_amdgcn_global_load_lds(                                       \
          (const __attribute__((address_space(1))) void*)(Bt + (size_t)(n0 + row) * 1536 + kk), \
          (__attribute__((address_space(3))) void*)(&Bls[bufi][rowblk * 32]), 16, 0, 0); \
    }

  STAGE(0, 0)
  int cur = 0;
  for (int kt = 0; kt < 48; ++kt) {
    // bar1: all waves' reads of buf[cur^1] retired -> safe to re-stage
    __builtin_amdgcn_s_barrier();
    if (kt < 47) {
      STAGE(cur ^ 1, (kt + 1) * 32)
      asm volatile("s_waitcnt vmcnt(4)" ::: "memory");   // wait prev 4, keep new 4 in flight
    } else {
      asm volatile("s_waitcnt vmcnt(0)" ::: "memory");   // last tile: drain
    }
    // bar2: current buffer's loads complete block-wide
    __builtin_amdgcn_s_barrier();
    __builtin_amdgcn_sched_barrier(0);
    short8v af[4], bf[4];
    #pragma unroll
    for (int mi = 0; mi < 4; ++mi)
      af[mi] = *(const short8v*)(&Als[cur][(wr * 64 + mi * 16 + (lane & 15)) * 32 + soff]);
    #pragma unroll
    for (int ni = 0; ni < 4; ++ni)
      bf[ni] = *(const short8v*)(&Bls[cur][(wc * 64 + ni * 16 + (lane & 15)) * 32 + soff]);
    #pragma unroll
    for (int mi = 0; mi < 4; ++mi)
      #pragma unroll
      for (int ni = 0; ni < 4; ++ni)
        acc[mi][ni] = __builtin_amdgcn_mfma_f32_16x16x32_bf16(af[mi], bf[ni], acc[mi][ni], 0, 0, 0);
    cur ^= 1;
  }
  #undef STAGE

  // epilogue: out = acc + x*D  (C/D layout: col=lane&15, row=(lane>>4)*4+r)
  #pragma unroll
  for (int ni = 0; ni < 4; ++ni) {
    const int col = n0 + wc * 64 + ni * 16 + (lane & 15);
    const float dcol = Dv[col];
    #pragma unroll
    for (int mi = 0; mi < 4; ++mi) {
      #pragma unroll
      for (int r = 0; r < 4; ++r) {
        const int row = m0 + wr * 64 + mi * 16 + (lane >> 4) * 4 + r;
        const size_t idx = (size_t)row * 768 + col;
        out[idx] = acc[mi][ni][r] + x[idx] * dcol;
      }
    }
  }
}

// ---------------------------------------------------------------------------
extern "C" void kernel_launch(void* const* d_in, const int* in_sizes, int n_in,
                              void* d_out, int out_size, void* d_ws, size_t ws_size,
                              hipStream_t stream) {
  const float* x     = (const float*)d_in[0];
  const float* Wg    = (const float*)d_in[1];
  const float* bg    = (const float*)d_in[2];
  const float* alpha = (const float*)d_in[3];
  const float* beta  = (const float*)d_in[4];
  const float* Wout  = (const float*)d_in[5];
  const float* Dv    = (const float*)d_in[6];
  const int*   kp    = (const int*)d_in[7];
  float* out = (float*)d_out;

  // workspace layout (~195 MiB)
  //   xT  aliases A   (xT dead before A is written by transpose_uv)
  //   partial aliases uv (partial consumed by pool_reduce before pde writes uv)
  char* ws = (char*)d_ws;
  unsigned short* A   = (unsigned short*)(ws);                 // 32768*1536*2   = 100663296
  float* xT           = (float*)(ws);                          // 8*768*4096*4   (alias A)
  unsigned short* uv  = (unsigned short*)(ws + 100663296);     // 8*1536*4096*2  = 100663296
  float* partial      = (float*)(ws + 100663296);              // 64*8*768*4     (alias uv)
  unsigned short* Wb  = (unsigned short*)(ws + 201326592);     // 768*1536*2     = 2359296
  float* pooled       = (float*)(ws + 203685888);              // 6144*4
  float* gam          = (float*)(ws + 203710464);              // 6144*4

  transpose_x_kernel<<<dim3(12, 64, 8), 256, 0, stream>>>(x, xT, partial);
  pool_reduce_kernel<<<24, 256, 0, stream>>>(partial, pooled);
  gamma_kernel<<<1536, 256, 0, stream>>>(pooled, Wg, bg, gam);
  cvt_bf16_kernel<<<(768 * 1536 + 255) / 256, 256, 0, stream>>>(Wout, Wb, 768 * 1536);
  pde_kernel<<<1536, 256, 0, stream>>>(xT, gam, alpha, beta, kp, uv);
  transpose_uv_kernel<<<dim3(64, 24, 8), 256, 0, stream>>>(uv, A);
  gemm_kernel<<<1536, 256, 0, stream>>>(A, Wb, x, Dv, out);
}

// Round 11
// 315.909 us; speedup vs baseline: 1.1477x; 1.1477x over previous
//
#include <hip/hip_runtime.h>
#include <hip/hip_bf16.h>
#include <math.h>

// ---------------------------------------------------------------------------
// RealSymplecticReactionDiffusion2D — round 10
//  B=8, N=4096 (64x64), d=768, k_steps=4 (read from device)
// Stages:
//  1) transpose_x (FUSED column-sum partials for mean-pool) -> xT + partial
//  2) pool_reduce  -> pooled[8][768]
//  3) gamma_kernel -> gamma[8][768]
//  4) cvt_bf16 (W_out -> bf16)
//  5) pde_kernel: ONE WAVE per (b,c) channel — 8x8 lane grid, 8x8 register
//     patch per lane; halo via 32 shfls; no LDS/barriers (R7, ~55us).
//  6) transpose_uv -> A [32768][1536] bf16
//  7) gemm_kernel (NEW): BK=32, FOUR LDS buffers (64KB), DEPTH-2 prefetch,
//     ONE barrier/iter. Tile t+2 staged while t+1 in flight and t computes —
//     each tile gets ~2 iterations to land (fixes R8's exposed-latency stall:
//     VALUBusy 9%, waves parked at vmcnt). Counted vmcnt(8)/4/0; R8 swizzle.
//  Aliases: xT ~ A  (xT dead before A written); partial ~ uv (dead before pde)
// ---------------------------------------------------------------------------

typedef __attribute__((ext_vector_type(8))) short short8v;
typedef __attribute__((ext_vector_type(4))) float float4v;

static __device__ __forceinline__ unsigned short f2bf(float f) {
  unsigned u = __builtin_bit_cast(unsigned, f);
  u += 0x7FFFu + ((u >> 16) & 1u);   // round-to-nearest-even
  return (unsigned short)(u >> 16);
}

static __device__ __forceinline__ float softplusf(float x) {
  return (x > 20.0f) ? x : log1pf(expf(x));
}

// ---------------- transpose x [B,N,768] -> xT [B,768,N]  (+ pool partials) --
__global__ __launch_bounds__(256) void transpose_x_kernel(const float* __restrict__ x,
                                                          float* __restrict__ xT,
                                                          float* __restrict__ partial) {
  __shared__ float tile[64][65];
  __shared__ float red[4][64];
  const int c0 = blockIdx.x * 64;   // 12 tiles
  const int n0 = blockIdx.y * 64;   // 64 tiles
  const int b  = blockIdx.z;        // 8
  const int tl = threadIdx.x & 63;
  const int tw = threadIdx.x >> 6;  // 0..3
  const float* src = x + ((size_t)b * 4096 + n0) * 768 + c0;
  float s = 0.0f;
  #pragma unroll
  for (int j = 0; j < 16; ++j) {
    const int n = j * 4 + tw;
    const float val = src[(size_t)n * 768 + tl];
    tile[n][tl] = val;
    s += val;
  }
  red[tw][tl] = s;
  __syncthreads();
  // partial[n-chunk][b][c] ; n-chunk = blockIdx.y (64 chunks)
  if (tw == 0) {
    partial[((size_t)blockIdx.y * 8 + b) * 768 + c0 + tl] =
        red[0][tl] + red[1][tl] + red[2][tl] + red[3][tl];
  }
  float* dst = xT + ((size_t)b * 768 + c0) * 4096 + n0;
  #pragma unroll
  for (int j = 0; j < 16; ++j) {
    const int cc = j * 4 + tw;
    dst[(size_t)cc * 4096 + tl] = tile[tl][cc];
  }
}

__global__ void pool_reduce_kernel(const float* __restrict__ partial, float* __restrict__ pooled) {
  const int idx = blockIdx.x * 256 + threadIdx.x;   // 0..6143 = b*768+c
  float s = 0.0f;
  #pragma unroll
  for (int j = 0; j < 64; ++j) s += partial[(size_t)j * 6144 + idx];
  pooled[idx] = s * (1.0f / 4096.0f);
}

// ---------------- diffusion gate ----------------
__global__ void gamma_kernel(const float* __restrict__ pooled, const float* __restrict__ Wg,
                             const float* __restrict__ bg, float* __restrict__ gamma) {
  // grid 1536 x 256 threads; each wave computes one output o = b*768 + j
  const int lane = threadIdx.x & 63;
  const int w = threadIdx.x >> 6;
  const int o = blockIdx.x * 4 + w;
  const int b = o / 768;
  const int j = o - b * 768;
  const float* pr = pooled + b * 768;
  const float* wr = Wg + (size_t)j * 768;
  float s = 0.0f;
  #pragma unroll
  for (int c = lane; c < 768; c += 64) s += pr[c] * wr[c];
  #pragma unroll
  for (int off = 32; off > 0; off >>= 1) s += __shfl_down(s, off);
  if (lane == 0) {
    float gin = s + bg[j];
    gamma[o] = fminf(softplusf(gin), 0.05f);
  }
}

// ---------------- W_out -> bf16 ----------------
__global__ void cvt_bf16_kernel(const float* __restrict__ src, unsigned short* __restrict__ dst, int n) {
  int i = blockIdx.x * 256 + threadIdx.x;
  if (i < n) dst[i] = f2bf(src[i]);
}

// ---------------- symplectic reaction-diffusion PDE (wave-per-channel) ------
__global__ __launch_bounds__(256, 2) void pde_kernel(
    const float* __restrict__ xT, const float* __restrict__ gamma,
    const float* __restrict__ alpha, const float* __restrict__ beta,
    const int* __restrict__ kp, unsigned short* __restrict__ uv) {
  const int w = threadIdx.x >> 6;          // wave 0..3 (independent channels)
  const int lane = threadIdx.x & 63;
  const int cidx = blockIdx.x * 4 + w;     // 0..6143
  const int b = cidx / 768;
  const int c = cidx - b * 768;
  const int lx = lane & 7;
  const int ly = lane >> 3;

  int ks = *kp; if (ks < 1) ks = 1;
  const float dt = 1.0f / (float)ks;
  const float hdt = 0.5f * dt;
  const float ae = 0.2f * tanhf(alpha[c]);
  const float be = fmaxf(softplusf(beta[c]), 1e-4f);
  const float g = gamma[b * 768 + c];
  const float c1n = -0.5f * dt * g;   // v -= c1*lap  ->  v += c1n*lap
  const float c2p = dt * g;

  const int laneL = (ly << 3) | ((lx + 7) & 7);
  const int laneR = (ly << 3) | ((lx + 1) & 7);
  const int laneU = (((ly + 7) & 7) << 3) | lx;   // holds rows above (row-1)
  const int laneD = (((ly + 1) & 7) << 3) | lx;   // holds rows below (row+1)

  float u[64], v[64];
  const float* xp = xT + ((size_t)b * 768 + c) * 4096;
  #pragma unroll
  for (int r = 0; r < 8; ++r) {
    const float4* src = (const float4*)(xp + (ly * 8 + r) * 64 + lx * 8);
    const float4 a0 = src[0], a1 = src[1];
    u[r * 8 + 0] = a0.x; u[r * 8 + 1] = a0.y; u[r * 8 + 2] = a0.z; u[r * 8 + 3] = a0.w;
    u[r * 8 + 4] = a1.x; u[r * 8 + 5] = a1.y; u[r * 8 + 6] = a1.z; u[r * 8 + 7] = a1.w;
  }
  #pragma unroll
  for (int i = 0; i < 64; ++i) v[i] = 0.0f;

  // G += COEF * lap(F): halo via 32 shfls, interior in-register.
  #define LAP_PHASE(F, G, COEF)                                               \
    {                                                                         \
      float lh[8], rh[8], uh[8], dh[8];                                       \
      _Pragma("unroll")                                                       \
      for (int r = 0; r < 8; ++r) {                                           \
        lh[r] = __shfl(F[r * 8 + 7], laneL);   /* left lane's right col  */   \
        rh[r] = __shfl(F[r * 8 + 0], laneR);   /* right lane's left col  */   \
        uh[r] = __shfl(F[56 + r], laneU);      /* up lane's bottom row, col r */ \
        dh[r] = __shfl(F[r], laneD);           /* down lane's top row, col r  */ \
      }                                                                       \
      _Pragma("unroll")                                                       \
      for (int r = 0; r < 8; ++r) {                                           \
        _Pragma("unroll")                                                     \
        for (int j = 0; j < 8; ++j) {                                         \
          const float lf = (j == 0) ? lh[r] : F[r * 8 + j - 1];               \
          const float rt = (j == 7) ? rh[r] : F[r * 8 + j + 1];               \
          const float up = (r == 0) ? uh[j] : F[(r - 1) * 8 + j];             \
          const float dn = (r == 7) ? dh[j] : F[(r + 1) * 8 + j];             \
          const float lap = (lf + rt) + (up + dn) - 4.0f * F[r * 8 + j];      \
          G[r * 8 + j] = fmaf((COEF), lap, G[r * 8 + j]);                     \
        }                                                                     \
      }                                                                       \
    }

  for (int s = 0; s < ks; ++s) {
    #pragma unroll
    for (int i = 0; i < 64; ++i) {
      const float q = u[i] * u[i] + v[i] * v[i];
      const float rate = fminf(fmaxf(ae - be * q, -1.0f), 1.0f);
      const float t = hdt * rate;
      u[i] = fmaf(t, u[i], u[i]);
      v[i] = fmaf(t, v[i], v[i]);
    }
    LAP_PHASE(u, v, c1n)
    LAP_PHASE(v, u, c2p)
    LAP_PHASE(u, v, c1n)
    #pragma unroll
    for (int i = 0; i < 64; ++i) {
      const float q = u[i] * u[i] + v[i] * v[i];
      const float rate = fminf(fmaxf(ae - be * q, -1.0f), 1.0f);
      const float t = hdt * rate;
      u[i] = fmaf(t, u[i], u[i]);
      v[i] = fmaf(t, v[i], v[i]);
    }
  }
  #undef LAP_PHASE

  // write out channel-major bf16: uv[b][c][n] = u, uv[b][768+c][n] = v
  unsigned short* up_ = uv + ((size_t)b * 1536 + c) * 4096;
  unsigned short* vp_ = up_ + (size_t)768 * 4096;
  #pragma unroll
  for (int r = 0; r < 8; ++r) {
    const int off = (ly * 8 + r) * 64 + lx * 8;
    short8v us, vs;
    #pragma unroll
    for (int j = 0; j < 8; ++j) {
      us[j] = (short)f2bf(u[r * 8 + j]);
      vs[j] = (short)f2bf(v[r * 8 + j]);
    }
    *(short8v*)(up_ + off) = us;
    *(short8v*)(vp_ + off) = vs;
  }
}

// ---------------- transpose uv [8][1536][4096] -> A [32768][1536] ----------------
__global__ void transpose_uv_kernel(const unsigned short* __restrict__ src,
                                    unsigned short* __restrict__ dst) {
  // grid (64, 24, 8), block 256
  __shared__ unsigned short tile[64][66];
  const int n0 = blockIdx.x * 64;
  const int k0 = blockIdx.y * 64;
  const int b = blockIdx.z;
  const int tx = threadIdx.x & 63;
  const int ty = threadIdx.x >> 6;   // 0..3
  const size_t sbase = ((size_t)b * 1536 + k0) * 4096 + n0;
  #pragma unroll
  for (int j = 0; j < 16; ++j) {
    const int k = ty + 4 * j;
    tile[k][tx] = src[sbase + (size_t)k * 4096 + tx];
  }
  __syncthreads();
  const size_t dbase = ((size_t)b * 4096 + n0) * 1536 + k0;
  #pragma unroll
  for (int j = 0; j < 16; ++j) {
    const int n = ty + 4 * j;
    dst[dbase + (size_t)n * 1536 + tx] = tile[tx][n];
  }
}

// ---------------- bf16 MFMA GEMM: out = A @ W^T + x*D ----------------
// BK=32, FOUR LDS buffers (4 x 16KB = 64KB) -> 2 blocks/CU.
// DEPTH-2 prefetch, ONE barrier/iter:
//   iter t: [STAGE tile t+2 into buf[(t+2)&3]] -> vmcnt(8) (drain tile t,
//   keep t+1,t+2 in flight) -> s_barrier -> compute buf[t&3].
// Write-safety: a wave STAGEs buf[(t+2)&3] only after crossing barrier(t),
// which guarantees ALL waves finished compute(t-1) — the last reader of that
// buffer (t-1 == t+3 == t+2+1 mod 4 distinct from t, t+1). Verified mod-4.
// Swizzle for 64B rows (4 x 16B slots): phys slot = logical ^ ((row>>1)&3)
//   (staging src xor (lane>>3)&3, read xor (lane>>1)&3; conflicts=0 in R10).
// XCD-chunked remap (R6).
__global__ __launch_bounds__(256, 4) void gemm_kernel(
    const unsigned short* __restrict__ A,   // [32768][1536] bf16
    const unsigned short* __restrict__ Bt,  // [768][1536]  bf16 (W_out, B^T layout)
    const float* __restrict__ x,            // [32768][768]
    const float* __restrict__ Dv,           // [768]
    float* __restrict__ out) {              // [32768][768]
  __shared__ __align__(16) unsigned short Als[4][128 * 32];
  __shared__ __align__(16) unsigned short Bls[4][128 * 32];
  const int tid = threadIdx.x;
  const int lane = tid & 63;
  const int w = tid >> 6;       // wave 0..3
  const int wr = w >> 1;        // wave row (2x2 waves, each 64x64 of C)
  const int wc = w & 1;

  // XCD-chunked remap: id -> (m-block, n-block). 1536 blocks, 8 XCDs.
  const int id = blockIdx.x;
  const int xcd = id & 7;
  const int seq = id >> 3;          // 0..191
  const int nb = seq % 6;
  const int mb = (seq / 6) * 8 + xcd;
  const int m0 = mb * 128;
  const int n0 = nb * 128;

  // staging: lane covers row (lane>>2), phys slot (lane&3);
  // fetch global logical slot (lane&3)^((lane>>3)&3)
  const int src_col = (((lane & 3) ^ ((lane >> 3) & 3)) * 8);   // halfwords
  // read side: logical slot q = lane>>4, row-phase xor = (lane>>1)&3
  const int soff = ((lane >> 4) ^ ((lane >> 1) & 3)) * 8;       // halfwords

  float4v acc[4][4];
  #pragma unroll
  for (int a = 0; a < 4; ++a)
    #pragma unroll
    for (int bq = 0; bq < 4; ++bq)
      acc[a][bq] = (float4v){0.f, 0.f, 0.f, 0.f};

  // per-thread: 4 global_load_lds (2 A + 2 B), 16B each; tile = 16KB total
  #define STAGE(bufi, kbase)                                                  \
    _Pragma("unroll")                                                         \
    for (int i = 0; i < 2; ++i) {                                             \
      const int rowblk = (i * 4 + w) * 16;                                    \
      const int row = rowblk + (lane >> 2);                                   \
      const int kk = (kbase) + src_col;                                       \
      __builtin_amdgcn_global_load_lds(                                       \
          (const __attribute__((address_space(1))) void*)(A + (size_t)(m0 + row) * 1536 + kk), \
          (__attribute__((address_space(3))) void*)(&Als[bufi][rowblk * 32]), 16, 0, 0); \
      __builtin_amdgcn_global_load_lds(                                       \
          (const __attribute__((address_space(1))) void*)(Bt + (size_t)(n0 + row) * 1536 + kk), \
          (__attribute__((address_space(3))) void*)(&Bls[bufi][rowblk * 32]), 16, 0, 0); \
    }

  STAGE(0, 0)
  STAGE(1, 32)
  for (int kt = 0; kt < 48; ++kt) {
    if (kt < 46) {
      STAGE((kt + 2) & 3, (kt + 2) * 32)
      // in flight: tiles t(4), t+1(4), t+2(4) = 12 -> wait oldest 4 (tile t)
      asm volatile("s_waitcnt vmcnt(8)" ::: "memory");
    } else if (kt == 46) {
      asm volatile("s_waitcnt vmcnt(4)" ::: "memory");   // drain tile 46
    } else {
      asm volatile("s_waitcnt vmcnt(0)" ::: "memory");   // drain tile 47
    }
    // single barrier: tile t ready block-wide; buffer-overwrite safety by
    // mod-4 distance (see header comment).
    __builtin_amdgcn_s_barrier();
    __builtin_amdgcn_sched_barrier(0);
    const int cur = kt & 3;
    short8v af[4], bf[4];
    #pragma unroll
    for (int mi = 0; mi < 4; ++mi)
      af[mi] = *(const short8v*)(&Als[cur][(wr * 64 + mi * 16 + (lane & 15)) * 32 + soff]);
    #pragma unroll
    for (int ni = 0; ni < 4; ++ni)
      bf[ni] = *(const short8v*)(&Bls[cur][(wc * 64 + ni * 16 + (lane & 15)) * 32 + soff]);
    #pragma unroll
    for (int mi = 0; mi < 4; ++mi)
      #pragma unroll
      for (int ni = 0; ni < 4; ++ni)
        acc[mi][ni] = __builtin_amdgcn_mfma_f32_16x16x32_bf16(af[mi], bf[ni], acc[mi][ni], 0, 0, 0);
  }
  #undef STAGE

  // epilogue: out = acc + x*D  (C/D layout: col=lane&15, row=(lane>>4)*4+r)
  #pragma unroll
  for (int ni = 0; ni < 4; ++ni) {
    const int col = n0 + wc * 64 + ni * 16 + (lane & 15);
    const float dcol = Dv[col];
    #pragma unroll
    for (int mi = 0; mi < 4; ++mi) {
      #pragma unroll
      for (int r = 0; r < 4; ++r) {
        const int row = m0 + wr * 64 + mi * 16 + (lane >> 4) * 4 + r;
        const size_t idx = (size_t)row * 768 + col;
        out[idx] = acc[mi][ni][r] + x[idx] * dcol;
      }
    }
  }
}

// ---------------------------------------------------------------------------
extern "C" void kernel_launch(void* const* d_in, const int* in_sizes, int n_in,
                              void* d_out, int out_size, void* d_ws, size_t ws_size,
                              hipStream_t stream) {
  const float* x     = (const float*)d_in[0];
  const float* Wg    = (const float*)d_in[1];
  const float* bg    = (const float*)d_in[2];
  const float* alpha = (const float*)d_in[3];
  const float* beta  = (const float*)d_in[4];
  const float* Wout  = (const float*)d_in[5];
  const float* Dv    = (const float*)d_in[6];
  const int*   kp    = (const int*)d_in[7];
  float* out = (float*)d_out;

  // workspace layout (~195 MiB)
  //   xT  aliases A   (xT dead before A is written by transpose_uv)
  //   partial aliases uv (partial consumed by pool_reduce before pde writes uv)
  char* ws = (char*)d_ws;
  unsigned short* A   = (unsigned short*)(ws);                 // 32768*1536*2   = 100663296
  float* xT           = (float*)(ws);                          // 8*768*4096*4   (alias A)
  unsigned short* uv  = (unsigned short*)(ws + 100663296);     // 8*1536*4096*2  = 100663296
  float* partial      = (float*)(ws + 100663296);              // 64*8*768*4     (alias uv)
  unsigned short* Wb  = (unsigned short*)(ws + 201326592);     // 768*1536*2     = 2359296
  float* pooled       = (float*)(ws + 203685888);              // 6144*4
  float* gam          = (float*)(ws + 203710464);              // 6144*4

  transpose_x_kernel<<<dim3(12, 64, 8), 256, 0, stream>>>(x, xT, partial);
  pool_reduce_kernel<<<24, 256, 0, stream>>>(partial, pooled);
  gamma_kernel<<<1536, 256, 0, stream>>>(pooled, Wg, bg, gam);
  cvt_bf16_kernel<<<(768 * 1536 + 255) / 256, 256, 0, stream>>>(Wout, Wb, 768 * 1536);
  pde_kernel<<<1536, 256, 0, stream>>>(xT, gam, alpha, beta, kp, uv);
  transpose_uv_kernel<<<dim3(64, 24, 8), 256, 0, stream>>>(uv, A);
  gemm_kernel<<<1536, 256, 0, stream>>>(A, Wb, x, Dv, out);
}